// Round 2
// baseline (487.535 us; speedup 1.0000x reference)
//
#include <hip/hip_runtime.h>

// IDCT: out[b, c, hb*8+p, wb*8+q] = sum_{i,j} H[i*8+p] * x[bc*64 + i*8+j, hb, wb] * H[j*8+q]
// x:   [16, 192, 128, 128] fp32  (bc = b*3+c in [0,48))
// out: [16, 3, 1024, 1024] fp32
//
// Workgroup (256 thr) = one bc, one hb-pair {h0,h0+1}, all 128 wb.
// Input staged to LDS via global_load_lds width=16 (16B/lane coalesced),
// double-buffered across the 8 i-stages (8 channels/stage = 8KB).
// Compute reads LDS at stride-1 in wb (2-way bank alias = free).

#define PLANE 16384            // Hb*Wb = 128*128

__global__ __launch_bounds__(256, 4) void idct_kernel(const float* __restrict__ x,
                                                      const float* __restrict__ Hm,
                                                      float* __restrict__ out) {
    __shared__ float Hs[64];
    __shared__ __align__(16) float buf[2][2048];   // [dbuf][ch8*256 + row*128 + wb]

    const int t = threadIdx.x;
    const int w = t >> 6;          // wave id 0..3

    if (t < 64) Hs[t] = Hm[t];

    const int bc = blockIdx.x >> 6;        // 0..47
    const int h0 = (blockIdx.x & 63) * 2;  // block-row pair base

    const int wb = t & 127;
    const int hrow = t >> 7;               // 0 or 1
    const int hb = h0 + hrow;

    const size_t xbase = (size_t)bc * 64 * PLANE;

    // global_load_lds plan: 512 float4 per stage, li = k*256 + t.
    // float index in buf = li*4 = ch8*256 + row*128 + f4*4  (linear in li -> GLL-compatible)
    int goff[2];
#pragma unroll
    for (int k = 0; k < 2; ++k) {
        int li = k * 256 + t;
        int ch8 = li >> 6;
        int row = (li >> 5) & 1;
        int f4 = li & 31;
        goff[k] = ch8 * PLANE + (h0 + row) * 128 + f4 * 4;
    }

    auto stage = [&](int b, int i) {
        const float* g0 = x + xbase + (size_t)i * (8 * PLANE) + goff[0];
        const float* g1 = x + xbase + (size_t)i * (8 * PLANE) + goff[1];
        float* l0 = &buf[b][(w * 64) * 4];          // wave-uniform LDS base, k=0
        float* l1 = &buf[b][(256 + w * 64) * 4];    // k=1
        __builtin_amdgcn_global_load_lds((const __attribute__((address_space(1))) void*)g0,
                                         (__attribute__((address_space(3))) void*)l0, 16, 0, 0);
        __builtin_amdgcn_global_load_lds((const __attribute__((address_space(1))) void*)g1,
                                         (__attribute__((address_space(3))) void*)l1, 16, 0, 0);
    };

    stage(0, 0);

    float tmp[8][8];
#pragma unroll
    for (int p = 0; p < 8; ++p)
#pragma unroll
        for (int j = 0; j < 8; ++j) tmp[p][j] = 0.0f;

    __syncthreads();   // drains GLL (vmcnt) + Hs write

#pragma unroll
    for (int i = 0; i < 8; ++i) {
        const int cur = i & 1;
        if (i < 7) stage(cur ^ 1, i + 1);   // next stage flies under this one's compute
        const float* B = &buf[cur][hrow * 128 + wb];
        float v[8];
#pragma unroll
        for (int j = 0; j < 8; ++j) v[j] = B[j * 256];
#pragma unroll
        for (int p = 0; p < 8; ++p) {
            float h = Hs[i * 8 + p];
#pragma unroll
            for (int j = 0; j < 8; ++j) tmp[p][j] = fmaf(h, v[j], tmp[p][j]);
        }
        __syncthreads();   // drains next-stage GLL + protects dbuf reuse
    }

    // Stage 2: out[p][q] = sum_j tmp[p][j] * H[j][q]
    float* dst = out + (size_t)bc * (1024u * 1024u) + (size_t)(hb * 8) * 1024 + wb * 8;
#pragma unroll
    for (int p = 0; p < 8; ++p) {
        float o[8];
#pragma unroll
        for (int q = 0; q < 8; ++q) o[q] = 0.0f;
#pragma unroll
        for (int j = 0; j < 8; ++j) {
            float tv = tmp[p][j];
#pragma unroll
            for (int q = 0; q < 8; ++q) o[q] = fmaf(tv, Hs[j * 8 + q], o[q]);
        }
        float4* d = (float4*)(dst + (size_t)p * 1024);
        d[0] = make_float4(o[0], o[1], o[2], o[3]);
        d[1] = make_float4(o[4], o[5], o[6], o[7]);
    }
}

extern "C" void kernel_launch(void* const* d_in, const int* in_sizes, int n_in,
                              void* d_out, int out_size, void* d_ws, size_t ws_size,
                              hipStream_t stream) {
    const float* x = (const float*)d_in[0];
    const float* H = (const float*)d_in[1];
    float* out = (float*)d_out;

    idct_kernel<<<48 * 64, 256, 0, stream>>>(x, H, out);
}

// Round 3
// 98.387 us; speedup vs baseline: 4.9553x; 4.9553x over previous
//
#include <hip/hip_runtime.h>

// IDCT: out[bc, hb*8+p, wb*8+q] = sum_{i,j} H[i*8+p] * x[bc*64+i*8+j, hb, wb] * H[j*8+q]
// x: [48*64, 128, 128] fp32 (bc in [0,48)), out: [48, 1024, 1024] fp32
//
// Two-phase separable transform through LDS (keeps register pressure ~55,
// avoids the R1 spill disaster):
//   Phase 1: thread (j, g) loads float4 over wb for all i, computes T[p][j]
//            for 4 block-columns, writes to LDS T[p][j][wb].
//   Phase 2: thread (p, g) reads T rows, computes O[p][q], stores 32
//            contiguous floats (8x float4 per thread).
// Workgroup = one (bc, hb) row = 128 DCT blocks. Grid = 48*128 = 6144.

#define PLANE 16384  // 128*128

__global__ __launch_bounds__(256) void idct_kernel(const float* __restrict__ x,
                                                   const float* __restrict__ Hm,
                                                   float* __restrict__ out) {
    __shared__ float Hs[64];
    __shared__ __align__(16) float T[8 * 8 * 128];  // [p][j][wb], 32 KB

    const int t = threadIdx.x;
    if (t < 64) Hs[t] = Hm[t];

    const int bc = blockIdx.x >> 7;   // 0..47
    const int hb = blockIdx.x & 127;  // 0..127

    __syncthreads();  // Hs ready; nothing else in flight yet

    // ---- Phase 1: column transform. thread = (j = t>>5, g = t&31), wb = g*4+0..3
    {
        const int j = t >> 5;
        const int g = t & 31;
        const float* src = x + (size_t)(bc * 64 + j) * PLANE + hb * 128 + g * 4;
        float4 v[8];
#pragma unroll
        for (int i = 0; i < 8; ++i)
            v[i] = *(const float4*)(src + (size_t)i * (8 * PLANE));
#pragma unroll
        for (int p = 0; p < 8; ++p) {
            float4 acc = make_float4(0.f, 0.f, 0.f, 0.f);
#pragma unroll
            for (int i = 0; i < 8; ++i) {
                float h = Hs[i * 8 + p];
                acc.x = fmaf(h, v[i].x, acc.x);
                acc.y = fmaf(h, v[i].y, acc.y);
                acc.z = fmaf(h, v[i].z, acc.z);
                acc.w = fmaf(h, v[i].w, acc.w);
            }
            *(float4*)&T[p * 1024 + j * 128 + g * 4] = acc;
        }
    }

    __syncthreads();  // T ready (drains ds_writes; globals already consumed)

    // ---- Phase 2: row transform. thread = (p = t>>5, g = t&31), 4 blocks each
    {
        const int p = t >> 5;
        const int g = t & 31;
        union F4 { float4 v; float f[4]; };
        F4 tj[8];
#pragma unroll
        for (int j = 0; j < 8; ++j)
            tj[j].v = *(const float4*)&T[p * 1024 + j * 128 + g * 4];

        float* dst = out + (size_t)bc * (1024u * 1024u) + (size_t)(hb * 8 + p) * 1024 + g * 32;
#pragma unroll
        for (int k = 0; k < 4; ++k) {  // 4 blocks per thread
            float o[8];
#pragma unroll
            for (int q = 0; q < 8; ++q) o[q] = 0.f;
#pragma unroll
            for (int j = 0; j < 8; ++j) {
                float tv = tj[j].f[k];  // compile-time k after unroll -> registers
#pragma unroll
                for (int q = 0; q < 8; ++q) o[q] = fmaf(tv, Hs[j * 8 + q], o[q]);
            }
            float4* d = (float4*)(dst + k * 8);
            d[0] = make_float4(o[0], o[1], o[2], o[3]);
            d[1] = make_float4(o[4], o[5], o[6], o[7]);
        }
    }
}

extern "C" void kernel_launch(void* const* d_in, const int* in_sizes, int n_in,
                              void* d_out, int out_size, void* d_ws, size_t ws_size,
                              hipStream_t stream) {
    const float* x = (const float*)d_in[0];
    const float* H = (const float*)d_in[1];
    float* out = (float*)d_out;

    idct_kernel<<<48 * 128, 256, 0, stream>>>(x, H, out);
}

// Round 4
// 77.730 us; speedup vs baseline: 6.2721x; 1.2657x over previous
//
#include <hip/hip_runtime.h>

// IDCT: out[bc, hb*8+p, wb*8+q] = sum_{i,j} H[i*8+p] * x[bc*64+i*8+j, hb, wb] * H[j*8+q]
// x: [48*64, 128, 128] fp32, out: [48, 1024, 1024] fp32
//
// Two-phase separable transform through LDS. Workgroup = one (bc, hb) row.
//   Phase 1: thread (j, g) loads float4 over wb for all i (coalesced 512B/
//            half-wave), computes T[p][j] for 4 block-cols, writes LDS.
//   Phase 2: thread (p, g) produces float4 output chunks at index g+32k ->
//            each wave store instruction is 2x 512B contiguous (coalesced),
//            unlike the R0/R2 layout (64x16B scatter over 8KB) which capped
//            effective BW at 4.1 TB/s.

#define PLANE 16384  // 128*128

__global__ __launch_bounds__(256) void idct_kernel(const float* __restrict__ x,
                                                   const float* __restrict__ Hm,
                                                   float* __restrict__ out) {
    __shared__ float Hs[64];
    __shared__ __align__(16) float T[8 * 8 * 128];  // [p][j][wb], 32 KB

    const int t = threadIdx.x;
    if (t < 64) Hs[t] = Hm[t];

    const int bc = blockIdx.x >> 7;   // 0..47
    const int hb = blockIdx.x & 127;  // 0..127

    __syncthreads();  // Hs ready

    // ---- Phase 1: column transform. thread = (j = t>>5, g = t&31)
    {
        const int j = t >> 5;
        const int g = t & 31;
        const float* src = x + (size_t)(bc * 64 + j) * PLANE + hb * 128 + g * 4;
        float4 v[8];
#pragma unroll
        for (int i = 0; i < 8; ++i)
            v[i] = *(const float4*)(src + (size_t)i * (8 * PLANE));
#pragma unroll
        for (int p = 0; p < 8; ++p) {
            float4 acc = make_float4(0.f, 0.f, 0.f, 0.f);
#pragma unroll
            for (int i = 0; i < 8; ++i) {
                float h = Hs[i * 8 + p];
                acc.x = fmaf(h, v[i].x, acc.x);
                acc.y = fmaf(h, v[i].y, acc.y);
                acc.z = fmaf(h, v[i].z, acc.z);
                acc.w = fmaf(h, v[i].w, acc.w);
            }
            *(float4*)&T[p * 1024 + j * 128 + g * 4] = acc;
        }
    }

    __syncthreads();  // T ready

    // ---- Phase 2: row transform, coalesced stores.
    // thread = (p = t>>5, g = t&31); handles float4 chunks f = g + 32k.
    // f -> wb = f>>1 = (g>>1)+16k, q0 = (f&1)*4 = (g&1)*4 (constant per thread).
    {
        const int p = t >> 5;
        const int g = t & 31;
        const int q0 = (g & 1) * 4;
        const int wb0 = g >> 1;

        float hq[8][4];
#pragma unroll
        for (int j = 0; j < 8; ++j)
#pragma unroll
            for (int c = 0; c < 4; ++c) hq[j][c] = Hs[j * 8 + q0 + c];

        float* dst = out + (size_t)bc * (1024u * 1024u) + (size_t)(hb * 8 + p) * 1024;
#pragma unroll
        for (int k = 0; k < 8; ++k) {
            const int wb = wb0 + 16 * k;
            float tj[8];
#pragma unroll
            for (int j = 0; j < 8; ++j) tj[j] = T[p * 1024 + j * 128 + wb];
            float4 o = make_float4(0.f, 0.f, 0.f, 0.f);
#pragma unroll
            for (int j = 0; j < 8; ++j) {
                o.x = fmaf(tj[j], hq[j][0], o.x);
                o.y = fmaf(tj[j], hq[j][1], o.y);
                o.z = fmaf(tj[j], hq[j][2], o.z);
                o.w = fmaf(tj[j], hq[j][3], o.w);
            }
            *(float4*)(dst + (size_t)(g + 32 * k) * 4) = o;
        }
    }
}

extern "C" void kernel_launch(void* const* d_in, const int* in_sizes, int n_in,
                              void* d_out, int out_size, void* d_ws, size_t ws_size,
                              hipStream_t stream) {
    const float* x = (const float*)d_in[0];
    const float* H = (const float*)d_in[1];
    float* out = (float*)d_out;

    idct_kernel<<<48 * 128, 256, 0, stream>>>(x, H, out);
}

// Round 6
// 65.748 us; speedup vs baseline: 7.4152x; 1.1822x over previous
//
#include <hip/hip_runtime.h>

// IDCT: out[bc, hb*8+p, wb*8+q] = sum_{i,j} H[i*8+p] * x[bc*64+i*8+j, hb, wb] * H[j*8+q]
// x: [48*64, 128, 128] fp32, out: [48, 1024, 1024] fp32
//
// Two-phase separable transform through LDS, pipelined over ROWS hb-rows per
// block: next row's global loads are issued before phase-2 of the current row
// (read latency hides under phase-2 compute + stores). Phase-1 H coeffs come
// from uniform scalar loads (no entry barrier); phase-2 output stores are
// non-temporal (write-once data, keep L3 for the input stream).

#define PLANE 16384  // 128*128
#define ROWS 4

typedef float vf4 __attribute__((ext_vector_type(4)));  // native vec for nontemporal builtin

__global__ __launch_bounds__(256) void idct_kernel(const float* __restrict__ x,
                                                   const float* __restrict__ Hm,
                                                   float* __restrict__ out) {
    __shared__ float Hs[64];
    __shared__ __align__(16) float T[8 * 8 * 128];  // [p][j][wb], 32 KB

    const int t = threadIdx.x;
    const int bc = blockIdx.x >> 5;          // 0..47
    const int hb0 = (blockIdx.x & 31) * ROWS;

    // phase-1 mapping: (j1, g1); phase-2 mapping: (p2, g2) — same split
    const int j1 = t >> 5, g1 = t & 31;
    const int p2 = j1, g2 = g1;
    const int q0 = (g2 & 1) * 4;
    const int wb0 = g2 >> 1;

    if (t < 64) Hs[t] = Hm[t];

    const float* src = x + (size_t)(bc * 64 + j1) * PLANE + hb0 * 128 + g1 * 4;

    float4 v[8];
    auto loadrow = [&](int r) {
#pragma unroll
        for (int i = 0; i < 8; ++i)
            v[i] = *(const float4*)(src + (size_t)r * 128 + (size_t)i * (8 * PLANE));
    };
    auto phase1 = [&]() {
#pragma unroll
        for (int p = 0; p < 8; ++p) {
            float4 acc = make_float4(0.f, 0.f, 0.f, 0.f);
#pragma unroll
            for (int i = 0; i < 8; ++i) {
                float h = Hm[i * 8 + p];  // uniform affine index -> s_load
                acc.x = fmaf(h, v[i].x, acc.x);
                acc.y = fmaf(h, v[i].y, acc.y);
                acc.z = fmaf(h, v[i].z, acc.z);
                acc.w = fmaf(h, v[i].w, acc.w);
            }
            *(float4*)&T[p * 1024 + j1 * 128 + g1 * 4] = acc;
        }
    };

    loadrow(0);
    phase1();
    __syncthreads();  // T[row 0] + Hs ready

    float4 hq[8];
#pragma unroll
    for (int j = 0; j < 8; ++j) hq[j] = *(const float4*)&Hs[j * 8 + q0];

#pragma unroll
    for (int r = 0; r < ROWS; ++r) {
        if (r + 1 < ROWS) loadrow(r + 1);  // in flight under phase-2 of row r

        // ---- phase 2, row r: coalesced nt stores
        float* dst = out + (size_t)bc * (1024u * 1024u) + (size_t)((hb0 + r) * 8 + p2) * 1024;
#pragma unroll
        for (int k = 0; k < 8; ++k) {
            const int wb = wb0 + 16 * k;
            float tj[8];
#pragma unroll
            for (int j = 0; j < 8; ++j) tj[j] = T[p2 * 1024 + j * 128 + wb];
            float o0 = 0.f, o1 = 0.f, o2 = 0.f, o3 = 0.f;
#pragma unroll
            for (int j = 0; j < 8; ++j) {
                o0 = fmaf(tj[j], hq[j].x, o0);
                o1 = fmaf(tj[j], hq[j].y, o1);
                o2 = fmaf(tj[j], hq[j].z, o2);
                o3 = fmaf(tj[j], hq[j].w, o3);
            }
            vf4 o = {o0, o1, o2, o3};
            __builtin_nontemporal_store(o, (vf4*)(dst + (size_t)(g2 + 32 * k) * 4));
        }

        if (r + 1 < ROWS) {
            __syncthreads();  // everyone done reading T[row r]
            phase1();         // waits only on v-loads (stores issued after -> no drain)
            __syncthreads();  // T[row r+1] ready
        }
    }
}

extern "C" void kernel_launch(void* const* d_in, const int* in_sizes, int n_in,
                              void* d_out, int out_size, void* d_ws, size_t ws_size,
                              hipStream_t stream) {
    const float* x = (const float*)d_in[0];
    const float* H = (const float*)d_in[1];
    float* out = (float*)d_out;

    idct_kernel<<<48 * (128 / ROWS), 256, 0, stream>>>(x, H, out);
}